// Round 4
// baseline (387.769 us; speedup 1.0000x reference)
//
#include <hip/hip_runtime.h>

// CTC forward loss, log2-domain DP — R4: producer/consumer wave specialization.
// One block (8 waves, 512 thr) per batch element. Waves 1-7 gather+log2 the 65
// needed channels per t-row into double-buffered LDS segments (64 rows each);
// wave 0 runs the serial 511-step alpha chain from LDS, one segment behind.
// R3 (1 wave/block) was latency/occupancy-bound at ~150 us: 1 wave/CU cannot
// generate enough outstanding gathers to claim the per-CU HBM share.
// Numerics identical to R3 (absmax 0.0): log2-domain lse via v_exp_f32 /
// v_log_f32 amdgcn builtins (glibc macro collision blocks __exp2f -- R2).

constexpr int Bc = 256, Tc = 512, Cc = 512, Lc = 64;
constexpr int BLANK = Cc - 1;
constexpr float EPSF = 1e-7f;
constexpr float NEGI = -1e30f;
constexpr float LN2 = 0.6931471805599453f;
constexpr int SR = 64;               // t-rows per LDS segment
constexpr int NSEG = Tc / SR;        // 8 segments
constexpr int NW = 8;                // waves per block
constexpr int NPROD = NW - 1;        // producer waves in steady state

__device__ __forceinline__ float exp2_hw(float x) { return __builtin_amdgcn_exp2f(x); }
__device__ __forceinline__ float log2_hw(float x) { return __builtin_amdgcn_logf(x); }

__device__ __forceinline__ float lse2(float a, float b) {
    float m = fmaxf(a, b);
    return m + log2_hw(exp2_hw(a - m) + exp2_hw(b - m));
}
__device__ __forceinline__ float lse3(float a, float b, float c) {
    float m = fmaxf(fmaxf(a, b), c);
    return m + log2_hw(exp2_hw(a - m) + exp2_hw(b - m) + exp2_hw(c - m));
}

__global__ __launch_bounds__(NW * 64, 1) void ctc_fwd(
    const int* __restrict__ labels,      // [B, L]
    const float* __restrict__ yp,        // [B, T, C] softmax probs
    const int* __restrict__ in_len,      // [B, 1]
    const int* __restrict__ lab_len,     // [B, 1]
    float* __restrict__ out)             // [B, 1]
{
    __shared__ float sL[2][SR * 64];     // emit log2(p[t, lab_lane]) per seg
    __shared__ float sB[2][SR];          // emit log2(p[t, blank]) per seg

    const int b = blockIdx.x;
    const int tid = threadIdx.x;
    const int lane = tid & 63;
    const int wave = tid >> 6;

    const float* __restrict__ row0 = yp + (size_t)b * (size_t)(Tc * Cc);

    // Per-lane label (same for every wave). Reference runs the DP over the FULL
    // label array; lab_len only gates the final extraction.
    const int lab = labels[b * Lc + lane];
    const int labPrev = __shfl_up(lab, 1);
    const bool allow = (lane >= 1 && lab != BLANK && lab != labPrev);

    int til = in_len[b];  if (til > Tc) til = Tc;
    const int lln = lab_len[b];

    auto fillRow = [&](int buf, int t, int r) {
        float v  = row0[(size_t)t * Cc + lab];    // per-lane gather (~28 lines)
        float vb = row0[(size_t)t * Cc + BLANK];  // wave-uniform broadcast
        sL[buf][r * 64 + lane] = log2_hw(v + EPSF);
        if (lane == 0) sB[buf][r] = log2_hw(vb + EPSF);
    };

    // Prefill segment 0 with ALL waves.
    #pragma unroll 2
    for (int r = wave; r < SR; r += NW) fillRow(0, r, r);

    // t = 0 chain init (log2 domain) — direct global read, overlaps the fill.
    float aB, aL, aH = NEGI;
    {
        float eb0 = log2_hw(row0[BLANK] + EPSF);
        float el0 = log2_hw(row0[lab] + EPSF);
        aB = (lane == 0) ? eb0 : NEGI;
        aL = (lane == 0) ? el0 : NEGI;
    }

    __syncthreads();

    for (int s = 0; s < NSEG; ++s) {
        const int buf = s & 1;
        if (wave == 0) {
            // Consumer: serial alpha chain over segment s (from LDS).
            #pragma unroll 8
            for (int k = 0; k < SR; ++k) {
                int t = s * SR + k;
                float el = sL[buf][k * 64 + lane];  // 2-way bank alias: free
                float eb = sB[buf][k];              // same-addr broadcast: free

                float lp = __shfl_up(aL, 1);        // alpha[2i-1]
                lp = (lane == 0) ? NEGI : lp;
                float lpm = allow ? lp : NEGI;

                float nB = lse2(aB, lp) + eb;       // s=2i
                float nL = lse3(aL, aB, lpm) + el;  // s=2i+1
                float nH = lse2(aH, aL) + eb;       // s=128 (lane 63)
                if (t >= 1 && t < til) { aB = nB; aL = nL; aH = nH; }
            }
        } else if (s + 1 < NSEG) {
            // Producers: fill segment s+1 into the other buffer.
            const int tb = (s + 1) * SR;
            #pragma unroll 2
            for (int r = wave - 1; r < SR; r += NPROD) fillRow(buf ^ 1, tb + r, r);
        }
        __syncthreads();
    }

    // Final states 2*lab_len and 2*lab_len-1 (log2 domain).
    if (wave == 0) {
        float v1a = __shfl(aB, lln & 63);
        float v1b = __shfl(aH, 63);
        float v1 = (lln >= 64) ? v1b : v1a;
        float v2 = (lln >= 1) ? __shfl(aL, (lln - 1) & 63) : NEGI;
        if (lane == 0) out[b] = -LN2 * lse2(v1, v2);
    }
}

extern "C" void kernel_launch(void* const* d_in, const int* in_sizes, int n_in,
                              void* d_out, int out_size, void* d_ws, size_t ws_size,
                              hipStream_t stream) {
    const int*   y_true       = (const int*)d_in[0];    // [B, L] int32
    const float* y_pred       = (const float*)d_in[1];  // [B, T, C] f32
    const int*   input_length = (const int*)d_in[2];    // [B, 1] int32
    const int*   label_length = (const int*)d_in[3];    // [B, 1] int32
    float*       out          = (float*)d_out;          // [B, 1] f32

    ctc_fwd<<<Bc, NW * 64, 0, stream>>>(y_true, y_pred, input_length, label_length, out);
}